// Round 3
// baseline (211.739 us; speedup 1.0000x reference)
//
#include <hip/hip_runtime.h>
#include <math.h>

namespace {

constexpr int Bn = 2, Hn = 128, Wn = 128, Cn = 256, Vn = 64;

__device__ __forceinline__ void load8(float* r, const float* p) {
    float4 a = *(const float4*)(p);
    float4 b = *(const float4*)(p + 4);
    r[0]=a.x; r[1]=a.y; r[2]=a.z; r[3]=a.w;
    r[4]=b.x; r[5]=b.y; r[6]=b.z; r[7]=b.w;
}

// 256 thr = 16 pixel-pairs x 16 channel-splits. Lane owns 2 pixels x 16 ch
// (as ch = cc*128 + s*8, cc=0..1). Score reduce = 4 shfl_xor steps over lane
// bits 0..3. Online softmax over the 5 di-rows (self slot seeds the state)
// keeps live scores at 10 regs instead of 52 -> VGPR<=128 -> 4 waves/SIMD
// with grid 1024 x 4 waves = 4096 waves. Value phase: lane owns 4 of V=64.
__global__ __launch_bounds__(256, 4)
void local_attn_kernel(const float* __restrict__ mainp,
                       const float* __restrict__ mainv,
                       const float* __restrict__ refp,
                       const float* __restrict__ refv,
                       float* __restrict__ outp)
{
    const int t = threadIdx.x;
    const int s = t & 15;       // channel/value split 0..15
    const int g = t >> 4;       // pixel-pair 0..15
    const int blk = blockIdx.x; // 0 .. B*H*4-1
    const int wt = blk & 3;
    const int h  = (blk >> 2) & (Hn - 1);
    const int b  = blk >> 9;
    const int w0 = wt * 32 + g * 2;     // px0 = w0, px1 = w0+1
    const int rowbase = b * Hn + h;

    // main channels for both pixels: 16 ch each (cc*128 + s*8)
    float m0[16], m1[16];
    const float* mp = mainp + ((size_t)rowbase * Wn + w0) * Cn + s * 8;
    load8(m0,     mp);
    load8(m0 + 8, mp + 128);
    load8(m1,     mp + Cn);
    load8(m1 + 8, mp + Cn + 128);

    // self scores (slot 25): full dot via 4-step shuffle reduce
    float self0 = 0.f, self1 = 0.f;
    #pragma unroll
    for (int c = 0; c < 16; ++c) {
        self0 = fmaf(m0[c], m0[c], self0);
        self1 = fmaf(m1[c], m1[c], self1);
    }
    #pragma unroll
    for (int k = 1; k < 16; k <<= 1) {
        self0 += __shfl_xor(self0, k);
        self1 += __shfl_xor(self1, k);
    }

    // online-softmax state seeded with the self slot (weight exp(0)=1)
    float mx0 = self0, mx1 = self1, den0 = 1.f, den1 = 1.f;
    float acc0[4], acc1[4];
    {
        const float* mvp = mainv + ((size_t)rowbase * Wn + w0) * Vn + s * 4;
        float4 a = *(const float4*)(mvp);
        float4 c = *(const float4*)(mvp + Vn);
        acc0[0]=a.x; acc0[1]=a.y; acc0[2]=a.z; acc0[3]=a.w;
        acc1[0]=c.x; acc1[1]=c.y; acc1[2]=c.z; acc1[3]=c.w;
    }

    #pragma unroll
    for (int di = 0; di < 5; ++di) {
        const int hh = h + di - 2;
        const bool rowok = (unsigned)hh < (unsigned)Hn;
        const size_t rbase = (size_t)(b * Hn + (rowok ? hh : 0)) * Wn;
        const float* rp = refp + rbase * Cn + s * 8;

        // ---- scores for this di row (zero for padded slots, like reference)
        float sc0[5] = {0,0,0,0,0}, sc1[5] = {0,0,0,0,0};
        #pragma unroll
        for (int cc = 0; cc < 2; ++cc) {
            const float* mm0 = m0 + cc * 8;
            const float* mm1 = m1 + cc * 8;
            #pragma unroll
            for (int o = 0; o < 6; ++o) {
                const int col = w0 - 2 + o;
                float r[8];
                #pragma unroll
                for (int c = 0; c < 8; ++c) r[c] = 0.f;
                if (rowok && (unsigned)col < (unsigned)Wn)
                    load8(r, rp + (size_t)col * Cn + cc * 128);
                if (o < 5) {
                    float a = 0.f;
                    #pragma unroll
                    for (int c = 0; c < 8; ++c) a = fmaf(mm0[c], r[c], a);
                    sc0[o] += a;
                }
                if (o >= 1) {
                    float a = 0.f;
                    #pragma unroll
                    for (int c = 0; c < 8; ++c) a = fmaf(mm1[c], r[c], a);
                    sc1[o - 1] += a;
                }
            }
        }
        #pragma unroll
        for (int k = 0; k < 5; ++k) {
            float v0 = sc0[k], v1 = sc1[k];
            v0 += __shfl_xor(v0, 1); v0 += __shfl_xor(v0, 2);
            v0 += __shfl_xor(v0, 4); v0 += __shfl_xor(v0, 8);
            v1 += __shfl_xor(v1, 1); v1 += __shfl_xor(v1, 2);
            v1 += __shfl_xor(v1, 4); v1 += __shfl_xor(v1, 8);
            sc0[k] = v0; sc1[k] = v1;
        }

        // ---- online softmax row update
        float rm0 = fmaxf(fmaxf(fmaxf(sc0[0], sc0[1]), fmaxf(sc0[2], sc0[3])), sc0[4]);
        float rm1 = fmaxf(fmaxf(fmaxf(sc1[0], sc1[1]), fmaxf(sc1[2], sc1[3])), sc1[4]);
        const float nm0 = fmaxf(mx0, rm0), nm1 = fmaxf(mx1, rm1);
        const float e0 = __expf(mx0 - nm0), e1 = __expf(mx1 - nm1);
        float wk0[5], wk1[5];
        float sum0 = 0.f, sum1 = 0.f;
        #pragma unroll
        for (int k = 0; k < 5; ++k) {
            wk0[k] = __expf(sc0[k] - nm0); sum0 += wk0[k];
            wk1[k] = __expf(sc1[k] - nm1); sum1 += wk1[k];
        }
        den0 = den0 * e0 + sum0;
        den1 = den1 * e1 + sum1;
        #pragma unroll
        for (int c = 0; c < 4; ++c) { acc0[c] *= e0; acc1[c] *= e1; }
        mx0 = nm0; mx1 = nm1;

        // ---- fused value row
        const float* rvp = refv + rbase * Vn + s * 4;
        #pragma unroll
        for (int o = 0; o < 6; ++o) {
            const int col = w0 - 2 + o;
            float4 rv = make_float4(0.f, 0.f, 0.f, 0.f);
            if (rowok && (unsigned)col < (unsigned)Wn)
                rv = *(const float4*)(rvp + (size_t)col * Vn);
            if (o < 5) {
                const float wk = wk0[o];
                acc0[0] = fmaf(wk, rv.x, acc0[0]); acc0[1] = fmaf(wk, rv.y, acc0[1]);
                acc0[2] = fmaf(wk, rv.z, acc0[2]); acc0[3] = fmaf(wk, rv.w, acc0[3]);
            }
            if (o >= 1) {
                const float wk = wk1[o - 1];
                acc1[0] = fmaf(wk, rv.x, acc1[0]); acc1[1] = fmaf(wk, rv.y, acc1[1]);
                acc1[2] = fmaf(wk, rv.z, acc1[2]); acc1[3] = fmaf(wk, rv.w, acc1[3]);
            }
        }
    }

    const float inv0 = 1.f / den0, inv1 = 1.f / den1;
    float* op = outp + ((size_t)rowbase * Wn + w0) * Vn + s * 4;
    float4 o0, o1;
    o0.x = acc0[0]*inv0; o0.y = acc0[1]*inv0; o0.z = acc0[2]*inv0; o0.w = acc0[3]*inv0;
    o1.x = acc1[0]*inv1; o1.y = acc1[1]*inv1; o1.z = acc1[2]*inv1; o1.w = acc1[3]*inv1;
    *(float4*)(op)      = o0;
    *(float4*)(op + Vn) = o1;
}

} // namespace

extern "C" void kernel_launch(void* const* d_in, const int* in_sizes, int n_in,
                              void* d_out, int out_size, void* d_ws, size_t ws_size,
                              hipStream_t stream)
{
    const float* mainp = (const float*)d_in[0];
    const float* mainv = (const float*)d_in[1];
    const float* refp  = (const float*)d_in[2];
    const float* refv  = (const float*)d_in[3];
    float* outp = (float*)d_out;

    dim3 grid(Bn * Hn * 4);   // 1024 blocks: one per 32-pixel row segment
    dim3 block(256);          // 16 pairs x 16 splits
    hipLaunchKernelGGL(local_attn_kernel, grid, block, 0, stream,
                       mainp, mainv, refp, refv, outp);
}

// Round 4
// 54.204 us; speedup vs baseline: 3.9063x; 3.9063x over previous
//
#include <hip/hip_runtime.h>
#include <math.h>

namespace {

constexpr int Bn = 2, Hn = 128, Wn = 128, Cn = 256, Vn = 64;

__device__ __forceinline__ void load8(float* r, const float* p) {
    float4 a = *(const float4*)(p);
    float4 b = *(const float4*)(p + 4);
    r[0]=a.x; r[1]=a.y; r[2]=a.z; r[3]=a.w;
    r[4]=b.x; r[5]=b.y; r[6]=b.z; r[7]=b.w;
}

// 256 thr = 16 pixel-pairs x 16 channel-splits. Lane owns 2 pixels x 16 ch
// (ch = cc*128 + s*8, cc=0..1). Score reduce = 4 shfl_xor steps over lane
// bits 0..3. Online softmax over the 5 di-rows (self slot seeds the state)
// keeps live scores small. NO forced occupancy cap: R2's __launch_bounds__
// (256,4) capped VGPR at 128 and the allocator spilled everything to scratch
// (455 MB writes, VALUBusy 0.1%). Let the allocator pick; grid gives 4096
// waves so anything <=128 VGPR yields 4 waves/SIMD, <=170 gives 3.
__global__ __launch_bounds__(256)
void local_attn_kernel(const float* __restrict__ mainp,
                       const float* __restrict__ mainv,
                       const float* __restrict__ refp,
                       const float* __restrict__ refv,
                       float* __restrict__ outp)
{
    const int t = threadIdx.x;
    const int s = t & 15;       // channel/value split 0..15
    const int g = t >> 4;       // pixel-pair 0..15
    const int blk = blockIdx.x; // 0 .. B*H*4-1
    const int wt = blk & 3;
    const int h  = (blk >> 2) & (Hn - 1);
    const int b  = blk >> 9;
    const int w0 = wt * 32 + g * 2;     // px0 = w0, px1 = w0+1
    const int rowbase = b * Hn + h;

    // main channels for both pixels: 16 ch each (cc*128 + s*8)
    float m0[16], m1[16];
    const float* mp = mainp + ((size_t)rowbase * Wn + w0) * Cn + s * 8;
    load8(m0,     mp);
    load8(m0 + 8, mp + 128);
    load8(m1,     mp + Cn);
    load8(m1 + 8, mp + Cn + 128);

    // self scores (slot 25): full dot via 4-step shuffle reduce
    float self0 = 0.f, self1 = 0.f;
    #pragma unroll
    for (int c = 0; c < 16; ++c) {
        self0 = fmaf(m0[c], m0[c], self0);
        self1 = fmaf(m1[c], m1[c], self1);
    }
    #pragma unroll
    for (int k = 1; k < 16; k <<= 1) {
        self0 += __shfl_xor(self0, k);
        self1 += __shfl_xor(self1, k);
    }

    // online-softmax state seeded with the self slot (weight exp(0)=1)
    float mx0 = self0, mx1 = self1, den0 = 1.f, den1 = 1.f;
    float acc0[4], acc1[4];
    {
        const float* mvp = mainv + ((size_t)rowbase * Wn + w0) * Vn + s * 4;
        float4 a = *(const float4*)(mvp);
        float4 c = *(const float4*)(mvp + Vn);
        acc0[0]=a.x; acc0[1]=a.y; acc0[2]=a.z; acc0[3]=a.w;
        acc1[0]=c.x; acc1[1]=c.y; acc1[2]=c.z; acc1[3]=c.w;
    }

    #pragma unroll
    for (int di = 0; di < 5; ++di) {
        const int hh = h + di - 2;
        const bool rowok = (unsigned)hh < (unsigned)Hn;
        const size_t rbase = (size_t)(b * Hn + (rowok ? hh : 0)) * Wn;
        const float* rp = refp + rbase * Cn + s * 8;

        // ---- scores for this di row (zero for padded slots, like reference)
        float sc0[5] = {0,0,0,0,0}, sc1[5] = {0,0,0,0,0};
        #pragma unroll
        for (int cc = 0; cc < 2; ++cc) {
            const float* mm0 = m0 + cc * 8;
            const float* mm1 = m1 + cc * 8;
            #pragma unroll
            for (int o = 0; o < 6; ++o) {
                const int col = w0 - 2 + o;
                float r[8];
                #pragma unroll
                for (int c = 0; c < 8; ++c) r[c] = 0.f;
                if (rowok && (unsigned)col < (unsigned)Wn)
                    load8(r, rp + (size_t)col * Cn + cc * 128);
                if (o < 5) {
                    float a = 0.f;
                    #pragma unroll
                    for (int c = 0; c < 8; ++c) a = fmaf(mm0[c], r[c], a);
                    sc0[o] += a;
                }
                if (o >= 1) {
                    float a = 0.f;
                    #pragma unroll
                    for (int c = 0; c < 8; ++c) a = fmaf(mm1[c], r[c], a);
                    sc1[o - 1] += a;
                }
            }
        }
        #pragma unroll
        for (int k = 0; k < 5; ++k) {
            float v0 = sc0[k], v1 = sc1[k];
            v0 += __shfl_xor(v0, 1); v0 += __shfl_xor(v0, 2);
            v0 += __shfl_xor(v0, 4); v0 += __shfl_xor(v0, 8);
            v1 += __shfl_xor(v1, 1); v1 += __shfl_xor(v1, 2);
            v1 += __shfl_xor(v1, 4); v1 += __shfl_xor(v1, 8);
            sc0[k] = v0; sc1[k] = v1;
        }

        // ---- online softmax row update
        float rm0 = fmaxf(fmaxf(fmaxf(sc0[0], sc0[1]), fmaxf(sc0[2], sc0[3])), sc0[4]);
        float rm1 = fmaxf(fmaxf(fmaxf(sc1[0], sc1[1]), fmaxf(sc1[2], sc1[3])), sc1[4]);
        const float nm0 = fmaxf(mx0, rm0), nm1 = fmaxf(mx1, rm1);
        const float e0 = __expf(mx0 - nm0), e1 = __expf(mx1 - nm1);
        float wk0[5], wk1[5];
        float sum0 = 0.f, sum1 = 0.f;
        #pragma unroll
        for (int k = 0; k < 5; ++k) {
            wk0[k] = __expf(sc0[k] - nm0); sum0 += wk0[k];
            wk1[k] = __expf(sc1[k] - nm1); sum1 += wk1[k];
        }
        den0 = den0 * e0 + sum0;
        den1 = den1 * e1 + sum1;
        #pragma unroll
        for (int c = 0; c < 4; ++c) { acc0[c] *= e0; acc1[c] *= e1; }
        mx0 = nm0; mx1 = nm1;

        // ---- fused value row
        const float* rvp = refv + rbase * Vn + s * 4;
        #pragma unroll
        for (int o = 0; o < 6; ++o) {
            const int col = w0 - 2 + o;
            float4 rv = make_float4(0.f, 0.f, 0.f, 0.f);
            if (rowok && (unsigned)col < (unsigned)Wn)
                rv = *(const float4*)(rvp + (size_t)col * Vn);
            if (o < 5) {
                const float wk = wk0[o];
                acc0[0] = fmaf(wk, rv.x, acc0[0]); acc0[1] = fmaf(wk, rv.y, acc0[1]);
                acc0[2] = fmaf(wk, rv.z, acc0[2]); acc0[3] = fmaf(wk, rv.w, acc0[3]);
            }
            if (o >= 1) {
                const float wk = wk1[o - 1];
                acc1[0] = fmaf(wk, rv.x, acc1[0]); acc1[1] = fmaf(wk, rv.y, acc1[1]);
                acc1[2] = fmaf(wk, rv.z, acc1[2]); acc1[3] = fmaf(wk, rv.w, acc1[3]);
            }
        }
    }

    const float inv0 = 1.f / den0, inv1 = 1.f / den1;
    float* op = outp + ((size_t)rowbase * Wn + w0) * Vn + s * 4;
    float4 o0, o1;
    o0.x = acc0[0]*inv0; o0.y = acc0[1]*inv0; o0.z = acc0[2]*inv0; o0.w = acc0[3]*inv0;
    o1.x = acc1[0]*inv1; o1.y = acc1[1]*inv1; o1.z = acc1[2]*inv1; o1.w = acc1[3]*inv1;
    *(float4*)(op)      = o0;
    *(float4*)(op + Vn) = o1;
}

} // namespace

extern "C" void kernel_launch(void* const* d_in, const int* in_sizes, int n_in,
                              void* d_out, int out_size, void* d_ws, size_t ws_size,
                              hipStream_t stream)
{
    const float* mainp = (const float*)d_in[0];
    const float* mainv = (const float*)d_in[1];
    const float* refp  = (const float*)d_in[2];
    const float* refv  = (const float*)d_in[3];
    float* outp = (float*)d_out;

    dim3 grid(Bn * Hn * 4);   // 1024 blocks: one per 32-pixel row segment
    dim3 block(256);          // 16 pairs x 16 splits
    hipLaunchKernelGGL(local_attn_kernel, grid, block, 0, stream,
                       mainp, mainv, refp, refv, outp);
}

// Round 5
// 41.694 us; speedup vs baseline: 5.0784x; 1.3000x over previous
//
#include <hip/hip_runtime.h>
#include <math.h>

namespace {

constexpr int Bn = 2, Hn = 128, Wn = 128, Cn = 256, Vn = 64;

__device__ __forceinline__ void load8(float* r, const float* p) {
    float4 a = *(const float4*)(p);
    float4 b = *(const float4*)(p + 4);
    r[0]=a.x; r[1]=a.y; r[2]=a.z; r[3]=a.w;
    r[4]=b.x; r[5]=b.y; r[6]=b.z; r[7]=b.w;
}

// 256 thr = 16 pixels x 16 channel-splits, ONE pixel per lane.
// R3 (2 px/lane) sat at VGPR=172 -> 2 waves/SIMD -> latency-bound (VALUBusy
// 26%). Dropping pairing halves per-lane state (m: 32->16 regs, one score
// set, one acc set) targeting <=102 VGPR -> 5 waves/SIMD. Grid 2048 blocks =
// 8192 waves, so occupancy is VGPR-bound only. di loop kept rolled
// (#pragma unroll 1) to bound in-flight loads; dj/cc statically unrolled.
__global__ __launch_bounds__(256)
void local_attn_kernel(const float* __restrict__ mainp,
                       const float* __restrict__ mainv,
                       const float* __restrict__ refp,
                       const float* __restrict__ refv,
                       float* __restrict__ outp)
{
    const int t = threadIdx.x;
    const int s = t & 15;       // channel/value split 0..15
    const int p = t >> 4;       // pixel 0..15
    const int blk = blockIdx.x; // 0 .. 2047
    const int seg = blk & 7;
    const int h   = (blk >> 3) & (Hn - 1);
    const int b   = blk >> 10;
    const int w   = seg * 16 + p;
    const int rowbase = b * Hn + h;

    // this lane's 16 main channels: ch = s*8 + c (c<8), 128 + s*8 + (c-8)
    float m[16];
    const float* mp = mainp + ((size_t)rowbase * Wn + w) * Cn + s * 8;
    load8(m,     mp);
    load8(m + 8, mp + 128);

    // self score (slot 25): full dot via 4-step shuffle reduce over s bits
    float self = 0.f;
    #pragma unroll
    for (int c = 0; c < 16; ++c) self = fmaf(m[c], m[c], self);
    self += __shfl_xor(self, 1);
    self += __shfl_xor(self, 2);
    self += __shfl_xor(self, 4);
    self += __shfl_xor(self, 8);

    // online-softmax state seeded with the self slot (weight exp(0)=1)
    float mx = self, den = 1.f;
    float acc[4];
    {
        const float* mvp = mainv + ((size_t)rowbase * Wn + w) * Vn + s * 4;
        float4 a = *(const float4*)(mvp);
        acc[0]=a.x; acc[1]=a.y; acc[2]=a.z; acc[3]=a.w;
    }

    #pragma unroll 1
    for (int di = 0; di < 5; ++di) {
        const int hh = h + di - 2;
        const bool rowok = (unsigned)hh < (unsigned)Hn;
        const size_t rbase = (size_t)(b * Hn + (rowok ? hh : 0)) * Wn;
        const float* rp = refp + rbase * Cn + s * 8;

        // ---- scores for this di row (zero for padded slots, like reference)
        float sc[5] = {0.f, 0.f, 0.f, 0.f, 0.f};
        #pragma unroll
        for (int dj = 0; dj < 5; ++dj) {
            const int col = w - 2 + dj;
            const bool ok = rowok && (unsigned)col < (unsigned)Wn;
            float r[8];
            #pragma unroll
            for (int c = 0; c < 8; ++c) r[c] = 0.f;
            if (ok) load8(r, rp + (size_t)col * Cn);
            float a = 0.f;
            #pragma unroll
            for (int c = 0; c < 8; ++c) a = fmaf(m[c], r[c], a);
            sc[dj] = a;
        }
        #pragma unroll
        for (int dj = 0; dj < 5; ++dj) {
            const int col = w - 2 + dj;
            const bool ok = rowok && (unsigned)col < (unsigned)Wn;
            float r[8];
            #pragma unroll
            for (int c = 0; c < 8; ++c) r[c] = 0.f;
            if (ok) load8(r, rp + (size_t)col * Cn + 128);
            float a = sc[dj];
            #pragma unroll
            for (int c = 0; c < 8; ++c) a = fmaf(m[8 + c], r[c], a);
            sc[dj] = a;
        }

        // reduce partial dots across the 16 split lanes (lane bits 0..3)
        #pragma unroll
        for (int k = 0; k < 5; ++k) {
            float v = sc[k];
            v += __shfl_xor(v, 1);
            v += __shfl_xor(v, 2);
            v += __shfl_xor(v, 4);
            v += __shfl_xor(v, 8);
            sc[k] = v;
        }

        // ---- online softmax row update
        const float rm = fmaxf(fmaxf(fmaxf(sc[0], sc[1]), fmaxf(sc[2], sc[3])), sc[4]);
        const float nm = fmaxf(mx, rm);
        const float e  = __expf(mx - nm);
        float wk[5];
        float sum = 0.f;
        #pragma unroll
        for (int k = 0; k < 5; ++k) { wk[k] = __expf(sc[k] - nm); sum += wk[k]; }
        den = den * e + sum;
        #pragma unroll
        for (int c = 0; c < 4; ++c) acc[c] *= e;
        mx = nm;

        // ---- fused value row (lane owns V channels s*4 .. s*4+3)
        const float* rvp = refv + rbase * Vn + s * 4;
        #pragma unroll
        for (int dj = 0; dj < 5; ++dj) {
            const int col = w - 2 + dj;
            float4 rv = make_float4(0.f, 0.f, 0.f, 0.f);
            if (rowok && (unsigned)col < (unsigned)Wn)
                rv = *(const float4*)(rvp + (size_t)col * Vn);
            const float wkj = wk[dj];
            acc[0] = fmaf(wkj, rv.x, acc[0]);
            acc[1] = fmaf(wkj, rv.y, acc[1]);
            acc[2] = fmaf(wkj, rv.z, acc[2]);
            acc[3] = fmaf(wkj, rv.w, acc[3]);
        }
    }

    const float inv = 1.f / den;
    float* op = outp + ((size_t)rowbase * Wn + w) * Vn + s * 4;
    float4 o;
    o.x = acc[0]*inv; o.y = acc[1]*inv; o.z = acc[2]*inv; o.w = acc[3]*inv;
    *(float4*)op = o;
}

} // namespace

extern "C" void kernel_launch(void* const* d_in, const int* in_sizes, int n_in,
                              void* d_out, int out_size, void* d_ws, size_t ws_size,
                              hipStream_t stream)
{
    const float* mainp = (const float*)d_in[0];
    const float* mainv = (const float*)d_in[1];
    const float* refp  = (const float*)d_in[2];
    const float* refv  = (const float*)d_in[3];
    float* outp = (float*)d_out;

    dim3 grid(Bn * Hn * 8);   // 2048 blocks: one per 16-pixel row segment
    dim3 block(256);          // 16 pixels x 16 splits
    hipLaunchKernelGGL(local_attn_kernel, grid, block, 0, stream,
                       mainp, mainv, refp, refv, outp);
}